// Round 6
// baseline (999.010 us; speedup 1.0000x reference)
//
#include <hip/hip_runtime.h>

#define N_SRC1 500000
#define N_DST1 100000
#define E1     1500000
#define N_DST2 20000
#define E2     200000
#define IN_F   128
#define H_F    256
#define N_CLS  47
#define NTOT   120000        // cnt1 ++ cnt2 scanned as one array (sum(cnt1)=E1)
#define HIST_B 2930          // ceil(E1/512)

// ---------------- workspace layout (4-byte elements) ----------------
#define OFF_CNT1  0
#define OFF_CNT2  100000     // contiguous with cnt1
#define OFF_RP1   120000
#define OFF_RP2   220000
#define OFF_FILL1 240000
#define OFF_FILL2 340000
#define OFF_WT1   360256     // 32768 ints = 256x256 bf16 [n][k], k=[Ws1;Wn1]
#define OFF_WT2   393024     // 24576 ints = 48x512 bf16 [n][k], k=[Ws2;Wn2]
#define OFF_CSR1  417600
#define OFF_CSR2  1917600
#define OFF_AGG1  2117600    // agg1b bf16 [N_DST1][128] (6.4M ints)
#define OFF_H     14917600   // N_DST1*H_F bf16 = 12.8M ints
#define ZERO_INTS 120000

typedef __attribute__((ext_vector_type(8))) short short8;
typedef __attribute__((ext_vector_type(4))) float floatx4;

static __device__ inline unsigned short f2bf(float f) {
  union { float f; unsigned u; } v; v.f = f;
  unsigned r = v.u + 0x7FFF + ((v.u >> 16) & 1);   // round-to-nearest-even
  return (unsigned short)(r >> 16);
}
static __device__ inline float bf2f(unsigned short u) {
  union { unsigned u; float f; } v; v.u = ((unsigned)u) << 16;
  return v.f;
}
static __device__ inline void f4acc(float4& a, const float4 b) {
  a.x += b.x; a.y += b.y; a.z += b.z; a.w += b.w;
}

// ---------------- fused init: hist + W1 conv + W2 conv (one dispatch) ----------
__global__ __launch_bounds__(512) void init_kernel(
    const int* __restrict__ dst1, const int* __restrict__ dst2,
    int* __restrict__ cnt1, int* __restrict__ cnt2,
    const float* __restrict__ Ws1, const float* __restrict__ Wn1,
    unsigned short* __restrict__ Wt,
    const float* __restrict__ Ws2, const float* __restrict__ Wn2,
    unsigned short* __restrict__ Wt2) {
  int bb = blockIdx.x;
  if (bb < HIST_B) {                       // histogram of both dst arrays
    int i = bb * 512 + threadIdx.x;
    if (i < E1) atomicAdd(&cnt1[dst1[i]], 1);
    if (i < E2) atomicAdd(&cnt2[dst2[i]], 1);
  } else if (bb < HIST_B + 128) {          // W1: Wt[n][k] bf16, k=[Ws1;Wn1]
    int q = bb - HIST_B;
    int n = q * 2 + (threadIdx.x >> 8);    // 0..255
    int k = threadIdx.x & 255;             // 0..255
    float v = (k < IN_F) ? Ws1[k * H_F + n] : Wn1[(k - IN_F) * H_F + n];
    Wt[n * 256 + k] = f2bf(v);
  } else {                                 // W2: Wt2[n][k] bf16 (n padded to 48)
    int n = bb - HIST_B - 128;             // 0..47
    int k = threadIdx.x;                   // 0..511
    float v = 0.f;
    if (n < N_CLS) v = (k < H_F) ? Ws2[k * N_CLS + n] : Wn2[(k - H_F) * N_CLS + n];
    Wt2[n * 512 + k] = f2bf(v);
  }
}

// ---------------- single-block fused exclusive scan over cnt1++cnt2 ------------
// replaces scanA+scanB+scanC (3 dependent dispatches -> 1).
// 1024 threads; thread t owns contiguous chunk [t*118, (t+1)*118) (120832 >= NTOT).
// pass1: chunk sums -> two-level (shfl + LDS) exclusive block scan ->
// pass2: L2-hot re-read, per-element running prefix, write rp/fill.
__global__ __launch_bounds__(1024) void scan_fused_kernel(
    const int* __restrict__ cnt,
    int* __restrict__ rp1, int* __restrict__ rp2,
    int* __restrict__ fill1, int* __restrict__ fill2) {
  __shared__ int wtot[16];
  int t = threadIdx.x;
  int beg = t * 118;
  int end = beg + 118; if (end > NTOT) end = NTOT;
  int s = 0;
  for (int i = beg; i < end; ++i) s += cnt[i];
  int lane = t & 63, wid = t >> 6;
  int ps = s;
#pragma unroll
  for (int off = 1; off < 64; off <<= 1) {
    int u = __shfl_up(ps, off, 64);
    if (lane >= off) ps += u;
  }
  if (lane == 63) wtot[wid] = ps;
  __syncthreads();
  if (t == 0) {
    int run = 0;
#pragma unroll
    for (int w = 0; w < 16; ++w) { int tmp = wtot[w]; wtot[w] = run; run += tmp; }
  }
  __syncthreads();
  int run = ps - s + wtot[wid];          // exclusive prefix of this thread's chunk
  for (int i = beg; i < end; ++i) {
    int v = cnt[i];
    if (i < N_DST1) { rp1[i] = run;            fill1[i] = run; }
    else            { rp2[i - N_DST1] = run - E1; fill2[i - N_DST1] = run - E1; }
    run += v;
  }
}

// ---------------- scatter src ids into CSR order ----------------
__global__ __launch_bounds__(256) void scatter_kernel(
    const int* __restrict__ src1, const int* __restrict__ dst1,
    const int* __restrict__ src2, const int* __restrict__ dst2,
    int* __restrict__ fill1, int* __restrict__ fill2,
    int* __restrict__ csr1, int* __restrict__ csr2) {
  int i = blockIdx.x * 256 + threadIdx.x;
  if (i < E1) {
    int p = atomicAdd(&fill1[dst1[i]], 1);
    csr1[p] = src1[i];
  }
  if (i < E2) {
    int p = atomicAdd(&fill2[dst2[i]], 1);
    csr2[p] = src2[i];
  }
}

// ---------------- layer-1 gather-reduce: one wave per dst ----------------
// 4-deep unrolled MLP; epilogue fuses 1/deg and bf16 conversion (agg1b bf16).
__global__ __launch_bounds__(256) void reduce1_kernel(
    const float* __restrict__ x, const int* __restrict__ csr,
    const int* __restrict__ rowptr, const int* __restrict__ cnt,
    unsigned short* __restrict__ aggb) {
  int w = (blockIdx.x * 256 + threadIdx.x) >> 6;
  if (w >= N_DST1) return;
  int lane = threadIdx.x & 63;
  int slot = lane >> 5;
  int f4   = lane & 31;
  const int* __restrict__ cp = csr + rowptr[w];
  int n = cnt[w];
  float4 a0 = make_float4(0.f,0.f,0.f,0.f), a1 = a0, a2 = a0, a3 = a0;
  int j = slot;
  for (; j + 6 < n; j += 8) {          // 4 rows per slot per round
    int s0 = cp[j];
    int s1 = cp[j + 2];
    int s2 = cp[j + 4];
    int s3 = cp[j + 6];
    float4 v0 = ((const float4*)(x + (size_t)s0 * IN_F))[f4];
    float4 v1 = ((const float4*)(x + (size_t)s1 * IN_F))[f4];
    float4 v2 = ((const float4*)(x + (size_t)s2 * IN_F))[f4];
    float4 v3 = ((const float4*)(x + (size_t)s3 * IN_F))[f4];
    f4acc(a0, v0); f4acc(a1, v1); f4acc(a2, v2); f4acc(a3, v3);
  }
  for (; j < n; j += 2) {
    int s = cp[j];
    float4 v = ((const float4*)(x + (size_t)s * IN_F))[f4];
    f4acc(a0, v);
  }
  f4acc(a0, a1); f4acc(a2, a3); f4acc(a0, a2);
  a0.x += __shfl(a0.x, lane ^ 32, 64);
  a0.y += __shfl(a0.y, lane ^ 32, 64);
  a0.z += __shfl(a0.z, lane ^ 32, 64);
  a0.w += __shfl(a0.w, lane ^ 32, 64);
  if (lane < 32) {
    float inv = 1.f / fmaxf((float)n, 1.f);
    ushort4 o;
    o.x = f2bf(a0.x * inv); o.y = f2bf(a0.y * inv);
    o.z = f2bf(a0.z * inv); o.w = f2bf(a0.w * inv);
    ((ushort4*)(aggb + (size_t)w * IN_F))[f4] = o;
  }
}

// ---------------- layer-1 MFMA GEMM: h = relu([x|aggb] @ [Ws;Wn] + b), h bf16 ---
#define ASTR 264   // A row stride in ushorts (256 + 8 pad)
#define WSTR 40    // W chunk row stride in ushorts (32 + 8 pad)
__global__ __launch_bounds__(256) void layer1_mfma_kernel(
    const float* __restrict__ x, const unsigned short* __restrict__ aggb,
    const unsigned short* __restrict__ Wt,
    const float* __restrict__ b, unsigned short* __restrict__ h) {
  __shared__ __align__(16) unsigned short As[64 * ASTR];   // 33.0 KB
  __shared__ __align__(16) unsigned short Wl[256 * WSTR];  // 20.0 KB
  int t    = threadIdx.x;
  int row0 = blockIdx.x * 64;
  // stage A = [x (convert) | aggb (plain bf16 copy)] row-major [64][256] (+pad)
#pragma unroll
  for (int i = 0; i < 8; ++i) {
    int g = t + i * 256;          // 0..2047
    int r = g >> 5, seg = g & 31, k0 = seg * 8;
    int grow = row0 + r;
    uint4 p;
    if (grow < N_DST1) {
      if (k0 < IN_F) {
        float4 v0 = ((const float4*)(x + (size_t)grow * IN_F + k0))[0];
        float4 v1 = ((const float4*)(x + (size_t)grow * IN_F + k0))[1];
        p.x = (unsigned)f2bf(v0.x) | ((unsigned)f2bf(v0.y) << 16);
        p.y = (unsigned)f2bf(v0.z) | ((unsigned)f2bf(v0.w) << 16);
        p.z = (unsigned)f2bf(v1.x) | ((unsigned)f2bf(v1.y) << 16);
        p.w = (unsigned)f2bf(v1.z) | ((unsigned)f2bf(v1.w) << 16);
      } else {
        p = *((const uint4*)(aggb + (size_t)grow * IN_F + (k0 - IN_F)));
      }
    } else {
      p.x = p.y = p.z = p.w = 0u;
    }
    *((uint4*)(As + r * ASTR + seg * 8)) = p;
  }

  floatx4 acc[4][4] = {};
  int wid = t >> 6, lane = t & 63;
  int quad = lane >> 4, l15 = lane & 15;

  for (int kc = 0; kc < 8; ++kc) {
    int k0 = kc * 32;
    __syncthreads();   // prior readers done (also orders A staging on kc==0)
#pragma unroll
    for (int rep = 0; rep < 4; ++rep) {
      int flat = t + rep * 256;     // 0..1023
      int n = flat >> 2, part = flat & 3;
      *((uint4*)(Wl + n * WSTR + part * 8)) =
          *((const uint4*)(Wt + n * 256 + k0 + part * 8));
    }
    __syncthreads();
    short8 af[4], bfr[4];
#pragma unroll
    for (int mi = 0; mi < 4; ++mi)
      af[mi] = *((const short8*)(As + (mi * 16 + l15) * ASTR + k0 + quad * 8));
#pragma unroll
    for (int ni = 0; ni < 4; ++ni)
      bfr[ni] = *((const short8*)(Wl + (wid * 64 + ni * 16 + l15) * WSTR + quad * 8));
#pragma unroll
    for (int mi = 0; mi < 4; ++mi)
#pragma unroll
      for (int ni = 0; ni < 4; ++ni)
        acc[mi][ni] = __builtin_amdgcn_mfma_f32_16x16x32_bf16(
            af[mi], bfr[ni], acc[mi][ni], 0, 0, 0);
  }

  // epilogue: C/D map col=lane&15, row=quad*4+reg; store bf16
  float bv[4];
#pragma unroll
  for (int ni = 0; ni < 4; ++ni) bv[ni] = b[wid * 64 + ni * 16 + l15];
#pragma unroll
  for (int mi = 0; mi < 4; ++mi) {
    int rbase = row0 + mi * 16 + quad * 4;
#pragma unroll
    for (int r = 0; r < 4; ++r) {
      int row = rbase + r;
      if (row < N_DST1) {
#pragma unroll
        for (int ni = 0; ni < 4; ++ni)
          h[(size_t)row * H_F + wid * 64 + ni * 16 + l15] =
              f2bf(fmaxf(acc[mi][ni][r] + bv[ni], 0.f));
      }
    }
  }
}

// ---------------- fused layer-2: gather-reduce (LDS) + MFMA GEMM ----------------
// phase 1: each wave gather-reduces 16 dst rows of h into bf16 LDS tile An
//          (pre-scaled by 1/deg; identical rounding to the old reduce2).
// phase 2: out = [h | An] @ [Ws2;Wn2] + b, one wave per 16 rows, N=48.
#define L2ASTR 264
__global__ __launch_bounds__(256) void layer2_fused_kernel(
    const unsigned short* __restrict__ h,   // bf16 [N_DST1][256]
    const int* __restrict__ csr, const int* __restrict__ rowptr,
    const int* __restrict__ cnt,
    const unsigned short* __restrict__ Wt2, // bf16 [48][512]
    const float* __restrict__ b, float* __restrict__ out) {
  __shared__ __align__(16) unsigned short An[64 * L2ASTR];  // 33.0 KB
  int t = threadIdx.x;
  int wid = t >> 6, lane = t & 63;
  int quad = lane >> 4, l15 = lane & 15;
  int blk = blockIdx.x * 64;

  // ---- phase 1: gather ----
  for (int rr = 0; rr < 16; ++rr) {
    int r = wid * 16 + rr;
    int d = blk + r;
    if (d < N_DST2) {
      const int* __restrict__ cp = csr + rowptr[d];
      int n = cnt[d];
      float4 a0 = make_float4(0.f,0.f,0.f,0.f), a1 = a0, a2 = a0, a3 = a0;
      int j = 0;
      for (; j + 3 < n; j += 4) {
        int s0 = cp[j], s1 = cp[j + 1], s2 = cp[j + 2], s3 = cp[j + 3];
        ushort4 v0 = *((const ushort4*)(h + (size_t)s0 * H_F + lane * 4));
        ushort4 v1 = *((const ushort4*)(h + (size_t)s1 * H_F + lane * 4));
        ushort4 v2 = *((const ushort4*)(h + (size_t)s2 * H_F + lane * 4));
        ushort4 v3 = *((const ushort4*)(h + (size_t)s3 * H_F + lane * 4));
        a0.x += bf2f(v0.x); a0.y += bf2f(v0.y); a0.z += bf2f(v0.z); a0.w += bf2f(v0.w);
        a1.x += bf2f(v1.x); a1.y += bf2f(v1.y); a1.z += bf2f(v1.z); a1.w += bf2f(v1.w);
        a2.x += bf2f(v2.x); a2.y += bf2f(v2.y); a2.z += bf2f(v2.z); a2.w += bf2f(v2.w);
        a3.x += bf2f(v3.x); a3.y += bf2f(v3.y); a3.z += bf2f(v3.z); a3.w += bf2f(v3.w);
      }
      for (; j < n; ++j) {
        int s = cp[j];
        ushort4 v = *((const ushort4*)(h + (size_t)s * H_F + lane * 4));
        a0.x += bf2f(v.x); a0.y += bf2f(v.y); a0.z += bf2f(v.z); a0.w += bf2f(v.w);
      }
      f4acc(a0, a1); f4acc(a2, a3); f4acc(a0, a2);
      float inv = 1.f / fmaxf((float)n, 1.f);
      ushort4 o;
      o.x = f2bf(a0.x * inv); o.y = f2bf(a0.y * inv);
      o.z = f2bf(a0.z * inv); o.w = f2bf(a0.w * inv);
      *((ushort4*)(An + r * L2ASTR + lane * 4)) = o;
    }
  }
  __syncthreads();

  // ---- phase 2: MFMA ----
  int base = blk + wid * 16;
  if (base >= N_DST2) return;
  int arow = base + l15;
  floatx4 acc[3] = {};
  // self half: k 0..255 from bf16 h (global, L2-hot contiguous rows)
  for (int kc = 0; kc < 8; ++kc) {
    short8 af = *((const short8*)(h + (size_t)arow * H_F + kc * 32 + quad * 8));
#pragma unroll
    for (int nt = 0; nt < 3; ++nt) {
      short8 bf = *((const short8*)(Wt2 + (nt * 16 + l15) * 512 + kc * 32 + quad * 8));
      acc[nt] = __builtin_amdgcn_mfma_f32_16x16x32_bf16(af, bf, acc[nt], 0, 0, 0);
    }
  }
  // neighbor half: k 256..511 from LDS An (pre-scaled bf16)
  for (int kc = 0; kc < 8; ++kc) {
    short8 af = *((const short8*)(An + (wid * 16 + l15) * L2ASTR + kc * 32 + quad * 8));
#pragma unroll
    for (int nt = 0; nt < 3; ++nt) {
      short8 bf = *((const short8*)(Wt2 + (nt * 16 + l15) * 512 + 256 + kc * 32 + quad * 8));
      acc[nt] = __builtin_amdgcn_mfma_f32_16x16x32_bf16(af, bf, acc[nt], 0, 0, 0);
    }
  }
  // epilogue: col = nt*16 + (lane&15), row = base + quad*4 + r
#pragma unroll
  for (int nt = 0; nt < 3; ++nt) {
    int col = nt * 16 + l15;
    if (col < N_CLS) {
      float bv = b[col];
#pragma unroll
      for (int r = 0; r < 4; ++r) {
        int orow = base + quad * 4 + r;
        out[(size_t)orow * N_CLS + col] = acc[nt][r] + bv;
      }
    }
  }
}

extern "C" void kernel_launch(void* const* d_in, const int* in_sizes, int n_in,
                              void* d_out, int out_size, void* d_ws, size_t ws_size,
                              hipStream_t stream) {
  const float* x   = (const float*)d_in[0];
  const float* Ws1 = (const float*)d_in[1];
  const float* Wn1 = (const float*)d_in[2];
  const float* b1  = (const float*)d_in[3];
  const float* Ws2 = (const float*)d_in[4];
  const float* Wn2 = (const float*)d_in[5];
  const float* b2  = (const float*)d_in[6];
  const int* src1  = (const int*)d_in[7];
  const int* dst1  = (const int*)d_in[8];
  const int* src2  = (const int*)d_in[9];
  const int* dst2  = (const int*)d_in[10];

  int*   wsI  = (int*)d_ws;
  int*   cnt1  = wsI + OFF_CNT1;
  int*   cnt2  = wsI + OFF_CNT2;
  int*   rp1   = wsI + OFF_RP1;
  int*   rp2   = wsI + OFF_RP2;
  int*   fill1 = wsI + OFF_FILL1;
  int*   fill2 = wsI + OFF_FILL2;
  unsigned short* Wt    = (unsigned short*)(wsI + OFF_WT1);
  unsigned short* Wt2   = (unsigned short*)(wsI + OFF_WT2);
  int*   csr1  = wsI + OFF_CSR1;
  int*   csr2  = wsI + OFF_CSR2;
  unsigned short* aggb  = (unsigned short*)(wsI + OFF_AGG1);
  unsigned short* h = (unsigned short*)(wsI + OFF_H);
  float* out   = (float*)d_out;

  hipMemsetAsync(wsI, 0, (size_t)ZERO_INTS * sizeof(int), stream);

  init_kernel<<<HIST_B + 128 + 48, 512, 0, stream>>>(
      dst1, dst2, cnt1, cnt2, Ws1, Wn1, Wt, Ws2, Wn2, Wt2);
  scan_fused_kernel<<<1, 1024, 0, stream>>>(cnt1, rp1, rp2, fill1, fill2);
  {
    int blocks = (E1 + 255) / 256;
    scatter_kernel<<<blocks, 256, 0, stream>>>(src1, dst1, src2, dst2,
                                               fill1, fill2, csr1, csr2);
  }
  {
    int blocks = (N_DST1 * 64 + 255) / 256;
    reduce1_kernel<<<blocks, 256, 0, stream>>>(x, csr1, rp1, cnt1, aggb);
  }
  {
    int blocks = (N_DST1 + 63) / 64;   // 1563
    layer1_mfma_kernel<<<blocks, 256, 0, stream>>>(x, aggb, Wt, b1, h);
  }
  {
    int blocks = (N_DST2 + 63) / 64;   // 313
    layer2_fused_kernel<<<blocks, 256, 0, stream>>>(h, csr2, rp2, cnt2, Wt2, b2, out);
  }
}

// Round 7
// 715.936 us; speedup vs baseline: 1.3954x; 1.3954x over previous
//
#include <hip/hip_runtime.h>

#define N_SRC1 500000
#define N_DST1 100000
#define E1     1500000
#define N_DST2 20000
#define E2     200000
#define IN_F   128
#define H_F    256
#define N_CLS  47
#define NTOT   120000        // cnt1 ++ cnt2 scanned as one array (sum(cnt1)=E1)
#define NB_SCAN 118          // ceil(120000/1024)
#define HIST_B 2930          // ceil(E1/512)

// ---------------- workspace layout (4-byte elements) ----------------
#define OFF_CNT1  0
#define OFF_CNT2  100000     // contiguous with cnt1
#define OFF_RP1   120000
#define OFF_RP2   220000
#define OFF_FILL1 240000
#define OFF_FILL2 340000
#define OFF_PART  360000     // 128 ints of scan partials
#define OFF_WT1   360256     // 32768 ints = 256x256 bf16 [n][k], k=[Ws1;Wn1]
#define OFF_WT2   393024     // 24576 ints = 48x512 bf16 [n][k], k=[Ws2;Wn2]
#define OFF_CSR1  417600
#define OFF_CSR2  1917600
#define OFF_AGG1  2117600    // agg1b bf16 [N_DST1][128] (6.4M ints); agg2b aliases
#define OFF_H     14917600   // N_DST1*H_F bf16 = 12.8M ints
#define ZERO_INTS 120000

typedef __attribute__((ext_vector_type(8))) short short8;
typedef __attribute__((ext_vector_type(4))) float floatx4;

static __device__ inline unsigned short f2bf(float f) {
  union { float f; unsigned u; } v; v.f = f;
  unsigned r = v.u + 0x7FFF + ((v.u >> 16) & 1);   // round-to-nearest-even
  return (unsigned short)(r >> 16);
}
static __device__ inline float bf2f(unsigned short u) {
  union { unsigned u; float f; } v; v.u = ((unsigned)u) << 16;
  return v.f;
}
static __device__ inline void f4acc(float4& a, const float4 b) {
  a.x += b.x; a.y += b.y; a.z += b.z; a.w += b.w;
}

// ---------------- fused init: hist + W1 conv + W2 conv (one dispatch) ----------
__global__ __launch_bounds__(512) void init_kernel(
    const int* __restrict__ dst1, const int* __restrict__ dst2,
    int* __restrict__ cnt1, int* __restrict__ cnt2,
    const float* __restrict__ Ws1, const float* __restrict__ Wn1,
    unsigned short* __restrict__ Wt,
    const float* __restrict__ Ws2, const float* __restrict__ Wn2,
    unsigned short* __restrict__ Wt2) {
  int bb = blockIdx.x;
  if (bb < HIST_B) {                       // histogram of both dst arrays
    int i = bb * 512 + threadIdx.x;
    if (i < E1) atomicAdd(&cnt1[dst1[i]], 1);
    if (i < E2) atomicAdd(&cnt2[dst2[i]], 1);
  } else if (bb < HIST_B + 128) {          // W1: Wt[n][k] bf16, k=[Ws1;Wn1]
    int q = bb - HIST_B;
    int n = q * 2 + (threadIdx.x >> 8);    // 0..255
    int k = threadIdx.x & 255;             // 0..255
    float v = (k < IN_F) ? Ws1[k * H_F + n] : Wn1[(k - IN_F) * H_F + n];
    Wt[n * 256 + k] = f2bf(v);
  } else {                                 // W2: Wt2[n][k] bf16 (n padded to 48)
    int n = bb - HIST_B - 128;             // 0..47
    int k = threadIdx.x;                   // 0..511
    float v = 0.f;
    if (n < N_CLS) v = (k < H_F) ? Ws2[k * N_CLS + n] : Wn2[(k - H_F) * N_CLS + n];
    Wt2[n * 512 + k] = f2bf(v);
  }
}

// ---------------- multi-block exclusive scan over cnt1++cnt2 ----------------
__global__ __launch_bounds__(1024) void scanA_kernel(
    const int* __restrict__ cnt, int* __restrict__ part) {
  __shared__ int wsum[16];
  int i = blockIdx.x * 1024 + threadIdx.x;
  int v = (i < NTOT) ? cnt[i] : 0;
  int lane = threadIdx.x & 63, wid = threadIdx.x >> 6;
#pragma unroll
  for (int off = 1; off < 64; off <<= 1) v += __shfl_xor(v, off, 64);
  if (lane == 0) wsum[wid] = v;
  __syncthreads();
  if (threadIdx.x == 0) {
    int s = 0;
#pragma unroll
    for (int w = 0; w < 16; ++w) s += wsum[w];
    part[blockIdx.x] = s;
  }
}

// wave-parallel scan of the 118 block partials
__global__ __launch_bounds__(64) void scanB_kernel(int* __restrict__ part) {
  int lane = threadIdx.x;
  int i1 = 64 + lane;
  int v0 = (lane < NB_SCAN) ? part[lane] : 0;
  int v1 = (i1 < NB_SCAN) ? part[i1] : 0;
  int s0 = v0;
#pragma unroll
  for (int off = 1; off < 64; off <<= 1) {
    int t = __shfl_up(s0, off, 64);
    if (lane >= off) s0 += t;
  }
  int total0 = __shfl(s0, 63, 64);
  int s1 = v1;
#pragma unroll
  for (int off = 1; off < 64; off <<= 1) {
    int t = __shfl_up(s1, off, 64);
    if (lane >= off) s1 += t;
  }
  if (lane < NB_SCAN) part[lane] = s0 - v0;            // exclusive
  if (i1 < NB_SCAN)   part[i1]   = total0 + s1 - v1;
}

__global__ __launch_bounds__(1024) void scanC_kernel(
    const int* __restrict__ cnt, const int* __restrict__ part,
    int* __restrict__ rp1, int* __restrict__ rp2,
    int* __restrict__ fill1, int* __restrict__ fill2) {
  __shared__ int wsum[16];
  int i = blockIdx.x * 1024 + threadIdx.x;
  int v = (i < NTOT) ? cnt[i] : 0;
  int lane = threadIdx.x & 63, wid = threadIdx.x >> 6;
  int s = v;
#pragma unroll
  for (int off = 1; off < 64; off <<= 1) {
    int t = __shfl_up(s, off, 64);
    if (lane >= off) s += t;
  }
  if (lane == 63) wsum[wid] = s;
  __syncthreads();
  if (threadIdx.x == 0) {
    int run = part[blockIdx.x];
#pragma unroll
    for (int w = 0; w < 16; ++w) { int t = wsum[w]; wsum[w] = run; run += t; }
  }
  __syncthreads();
  int excl = s - v + wsum[wid];
  if (i < N_DST1)      { rp1[i] = excl;          fill1[i] = excl; }
  else if (i < NTOT)   { rp2[i - N_DST1] = excl - E1; fill2[i - N_DST1] = excl - E1; }
}

// ---------------- scatter src ids into CSR order ----------------
__global__ __launch_bounds__(256) void scatter_kernel(
    const int* __restrict__ src1, const int* __restrict__ dst1,
    const int* __restrict__ src2, const int* __restrict__ dst2,
    int* __restrict__ fill1, int* __restrict__ fill2,
    int* __restrict__ csr1, int* __restrict__ csr2) {
  int i = blockIdx.x * 256 + threadIdx.x;
  if (i < E1) {
    int p = atomicAdd(&fill1[dst1[i]], 1);
    csr1[p] = src1[i];
  }
  if (i < E2) {
    int p = atomicAdd(&fill2[dst2[i]], 1);
    csr2[p] = src2[i];
  }
}

// ---------------- layer-1 gather-reduce: one wave per dst ----------------
// contiguous-half slot split (slot0 [0,h0), slot1 [h0,n)) with staged 6/2/1
// unroll: keeps up to 6 independent 512B row loads in flight per slot and
// cuts the 1-deep serial tail from ~3-4 stages to <=2.
// epilogue fuses 1/deg + bf16 (identical rounding point as before).
__global__ __launch_bounds__(256) void reduce1_kernel(
    const float* __restrict__ x, const int* __restrict__ csr,
    const int* __restrict__ rowptr, const int* __restrict__ cnt,
    unsigned short* __restrict__ aggb) {
  int w = (blockIdx.x * 256 + threadIdx.x) >> 6;
  if (w >= N_DST1) return;
  int lane = threadIdx.x & 63;
  int slot = lane >> 5;
  int f4   = lane & 31;
  const int* __restrict__ cp = csr + rowptr[w];
  int n = cnt[w];
  int h0 = (n + 1) >> 1;
  int j  = slot ? h0 : 0;
  int je = slot ? n  : h0;
  float4 a0 = make_float4(0.f,0.f,0.f,0.f);
  float4 a1 = a0, a2 = a0, a3 = a0, a4 = a0, a5 = a0;
  for (; j + 5 < je; j += 6) {
    int s0 = cp[j],     s1 = cp[j + 1], s2 = cp[j + 2];
    int s3 = cp[j + 3], s4 = cp[j + 4], s5 = cp[j + 5];
    float4 v0 = ((const float4*)(x + (size_t)s0 * IN_F))[f4];
    float4 v1 = ((const float4*)(x + (size_t)s1 * IN_F))[f4];
    float4 v2 = ((const float4*)(x + (size_t)s2 * IN_F))[f4];
    float4 v3 = ((const float4*)(x + (size_t)s3 * IN_F))[f4];
    float4 v4 = ((const float4*)(x + (size_t)s4 * IN_F))[f4];
    float4 v5 = ((const float4*)(x + (size_t)s5 * IN_F))[f4];
    f4acc(a0, v0); f4acc(a1, v1); f4acc(a2, v2);
    f4acc(a3, v3); f4acc(a4, v4); f4acc(a5, v5);
  }
  for (; j + 1 < je; j += 2) {
    int s0 = cp[j], s1 = cp[j + 1];
    float4 v0 = ((const float4*)(x + (size_t)s0 * IN_F))[f4];
    float4 v1 = ((const float4*)(x + (size_t)s1 * IN_F))[f4];
    f4acc(a0, v0); f4acc(a1, v1);
  }
  if (j < je) {
    int s0 = cp[j];
    float4 v0 = ((const float4*)(x + (size_t)s0 * IN_F))[f4];
    f4acc(a0, v0);
  }
  f4acc(a0, a1); f4acc(a2, a3); f4acc(a4, a5);
  f4acc(a0, a2); f4acc(a0, a4);
  a0.x += __shfl(a0.x, lane ^ 32, 64);
  a0.y += __shfl(a0.y, lane ^ 32, 64);
  a0.z += __shfl(a0.z, lane ^ 32, 64);
  a0.w += __shfl(a0.w, lane ^ 32, 64);
  if (lane < 32) {
    float inv = 1.f / fmaxf((float)n, 1.f);
    ushort4 o;
    o.x = f2bf(a0.x * inv); o.y = f2bf(a0.y * inv);
    o.z = f2bf(a0.z * inv); o.w = f2bf(a0.w * inv);
    ((ushort4*)(aggb + (size_t)w * IN_F))[f4] = o;
  }
}

// ---------------- layer-1 MFMA GEMM: h = relu([x|aggb] @ [Ws;Wn] + b), h bf16 ---
#define ASTR 264   // A row stride in ushorts (256 + 8 pad)
#define WSTR 40    // W chunk row stride in ushorts (32 + 8 pad)
__global__ __launch_bounds__(256) void layer1_mfma_kernel(
    const float* __restrict__ x, const unsigned short* __restrict__ aggb,
    const unsigned short* __restrict__ Wt,
    const float* __restrict__ b, unsigned short* __restrict__ h) {
  __shared__ __align__(16) unsigned short As[64 * ASTR];   // 33.0 KB
  __shared__ __align__(16) unsigned short Wl[256 * WSTR];  // 20.0 KB
  int t    = threadIdx.x;
  int row0 = blockIdx.x * 64;
  // stage A = [x (convert) | aggb (plain bf16 copy)] row-major [64][256] (+pad)
#pragma unroll
  for (int i = 0; i < 8; ++i) {
    int g = t + i * 256;          // 0..2047
    int r = g >> 5, seg = g & 31, k0 = seg * 8;
    int grow = row0 + r;
    uint4 p;
    if (grow < N_DST1) {
      if (k0 < IN_F) {
        float4 v0 = ((const float4*)(x + (size_t)grow * IN_F + k0))[0];
        float4 v1 = ((const float4*)(x + (size_t)grow * IN_F + k0))[1];
        p.x = (unsigned)f2bf(v0.x) | ((unsigned)f2bf(v0.y) << 16);
        p.y = (unsigned)f2bf(v0.z) | ((unsigned)f2bf(v0.w) << 16);
        p.z = (unsigned)f2bf(v1.x) | ((unsigned)f2bf(v1.y) << 16);
        p.w = (unsigned)f2bf(v1.z) | ((unsigned)f2bf(v1.w) << 16);
      } else {
        p = *((const uint4*)(aggb + (size_t)grow * IN_F + (k0 - IN_F)));
      }
    } else {
      p.x = p.y = p.z = p.w = 0u;
    }
    *((uint4*)(As + r * ASTR + seg * 8)) = p;
  }

  floatx4 acc[4][4] = {};
  int wid = t >> 6, lane = t & 63;
  int quad = lane >> 4, l15 = lane & 15;

  for (int kc = 0; kc < 8; ++kc) {
    int k0 = kc * 32;
    __syncthreads();   // prior readers done (also orders A staging on kc==0)
#pragma unroll
    for (int rep = 0; rep < 4; ++rep) {
      int flat = t + rep * 256;     // 0..1023
      int n = flat >> 2, part = flat & 3;
      *((uint4*)(Wl + n * WSTR + part * 8)) =
          *((const uint4*)(Wt + n * 256 + k0 + part * 8));
    }
    __syncthreads();
    short8 af[4], bfr[4];
#pragma unroll
    for (int mi = 0; mi < 4; ++mi)
      af[mi] = *((const short8*)(As + (mi * 16 + l15) * ASTR + k0 + quad * 8));
#pragma unroll
    for (int ni = 0; ni < 4; ++ni)
      bfr[ni] = *((const short8*)(Wl + (wid * 64 + ni * 16 + l15) * WSTR + quad * 8));
#pragma unroll
    for (int mi = 0; mi < 4; ++mi)
#pragma unroll
      for (int ni = 0; ni < 4; ++ni)
        acc[mi][ni] = __builtin_amdgcn_mfma_f32_16x16x32_bf16(
            af[mi], bfr[ni], acc[mi][ni], 0, 0, 0);
  }

  // epilogue: C/D map col=lane&15, row=quad*4+reg; store bf16
  float bv[4];
#pragma unroll
  for (int ni = 0; ni < 4; ++ni) bv[ni] = b[wid * 64 + ni * 16 + l15];
#pragma unroll
  for (int mi = 0; mi < 4; ++mi) {
    int rbase = row0 + mi * 16 + quad * 4;
#pragma unroll
    for (int r = 0; r < 4; ++r) {
      int row = rbase + r;
      if (row < N_DST1) {
#pragma unroll
        for (int ni = 0; ni < 4; ++ni)
          h[(size_t)row * H_F + wid * 64 + ni * 16 + l15] =
              f2bf(fmaxf(acc[mi][ni][r] + bv[ni], 0.f));
      }
    }
  }
}

// ---------------- layer-2 gather-reduce (bf16 h): one wave per dst ----------------
// 4-deep unroll; epilogue fuses 1/deg + bf16 (agg2b bf16, pre-scaled)
__global__ __launch_bounds__(256) void reduce2_kernel(
    const unsigned short* __restrict__ h, const int* __restrict__ csr,
    const int* __restrict__ rowptr, const int* __restrict__ cnt,
    unsigned short* __restrict__ agg2b) {
  int w = (blockIdx.x * 256 + threadIdx.x) >> 6;
  if (w >= N_DST2) return;
  int lane = threadIdx.x & 63;
  const int* __restrict__ cp = csr + rowptr[w];
  int n = cnt[w];
  float4 a0 = make_float4(0.f,0.f,0.f,0.f), a1 = a0, a2 = a0, a3 = a0;
  int j = 0;
  for (; j + 3 < n; j += 4) {
    int s0 = cp[j], s1 = cp[j + 1], s2 = cp[j + 2], s3 = cp[j + 3];
    ushort4 v0 = *((const ushort4*)(h + (size_t)s0 * H_F + lane * 4));
    ushort4 v1 = *((const ushort4*)(h + (size_t)s1 * H_F + lane * 4));
    ushort4 v2 = *((const ushort4*)(h + (size_t)s2 * H_F + lane * 4));
    ushort4 v3 = *((const ushort4*)(h + (size_t)s3 * H_F + lane * 4));
    a0.x += bf2f(v0.x); a0.y += bf2f(v0.y); a0.z += bf2f(v0.z); a0.w += bf2f(v0.w);
    a1.x += bf2f(v1.x); a1.y += bf2f(v1.y); a1.z += bf2f(v1.z); a1.w += bf2f(v1.w);
    a2.x += bf2f(v2.x); a2.y += bf2f(v2.y); a2.z += bf2f(v2.z); a2.w += bf2f(v2.w);
    a3.x += bf2f(v3.x); a3.y += bf2f(v3.y); a3.z += bf2f(v3.z); a3.w += bf2f(v3.w);
  }
  for (; j < n; ++j) {
    int s = cp[j];
    ushort4 v = *((const ushort4*)(h + (size_t)s * H_F + lane * 4));
    a0.x += bf2f(v.x); a0.y += bf2f(v.y); a0.z += bf2f(v.z); a0.w += bf2f(v.w);
  }
  f4acc(a0, a1); f4acc(a2, a3); f4acc(a0, a2);
  float inv = 1.f / fmaxf((float)n, 1.f);
  ushort4 o;
  o.x = f2bf(a0.x * inv); o.y = f2bf(a0.y * inv);
  o.z = f2bf(a0.z * inv); o.w = f2bf(a0.w * inv);
  ((ushort4*)(agg2b + (size_t)w * H_F))[lane] = o;
}

// ---------------- layer-2 MFMA GEMM: out = [h|agg2b] @ [Ws2;Wn2] + b ----------------
// one wave per 16 rows; N=48 (3 tiles of 16); both halves straight bf16 loads
__global__ __launch_bounds__(256) void layer2_mfma_kernel(
    const unsigned short* __restrict__ h,     // bf16 [N_DST1][256]
    const unsigned short* __restrict__ agg2b, // bf16 [N_DST2][256], pre-scaled
    const unsigned short* __restrict__ Wt2,   // bf16 [48][512]
    const float* __restrict__ b, float* __restrict__ out) {
  int t = threadIdx.x;
  int wid = t >> 6, lane = t & 63;
  int quad = lane >> 4, l15 = lane & 15;
  int base = blockIdx.x * 64 + wid * 16;
  if (base >= N_DST2) return;
  int arow = base + l15;                    // this lane's A row
  floatx4 acc[3] = {};

  // self half: k 0..255 from bf16 h
  for (int kc = 0; kc < 8; ++kc) {
    short8 af = *((const short8*)(h + (size_t)arow * H_F + kc * 32 + quad * 8));
#pragma unroll
    for (int nt = 0; nt < 3; ++nt) {
      short8 bf = *((const short8*)(Wt2 + (nt * 16 + l15) * 512 + kc * 32 + quad * 8));
      acc[nt] = __builtin_amdgcn_mfma_f32_16x16x32_bf16(af, bf, acc[nt], 0, 0, 0);
    }
  }
  // neighbor half: k 256..511 from pre-scaled bf16 agg2b
  for (int kc = 0; kc < 8; ++kc) {
    short8 af = *((const short8*)(agg2b + (size_t)arow * H_F + kc * 32 + quad * 8));
#pragma unroll
    for (int nt = 0; nt < 3; ++nt) {
      short8 bf = *((const short8*)(Wt2 + (nt * 16 + l15) * 512 + 256 + kc * 32 + quad * 8));
      acc[nt] = __builtin_amdgcn_mfma_f32_16x16x32_bf16(af, bf, acc[nt], 0, 0, 0);
    }
  }
  // epilogue: col = nt*16 + (lane&15), row = base + quad*4 + r
#pragma unroll
  for (int nt = 0; nt < 3; ++nt) {
    int col = nt * 16 + l15;
    if (col < N_CLS) {
      float bv = b[col];
#pragma unroll
      for (int r = 0; r < 4; ++r) {
        int orow = base + quad * 4 + r;
        out[(size_t)orow * N_CLS + col] = acc[nt][r] + bv;
      }
    }
  }
}

extern "C" void kernel_launch(void* const* d_in, const int* in_sizes, int n_in,
                              void* d_out, int out_size, void* d_ws, size_t ws_size,
                              hipStream_t stream) {
  const float* x   = (const float*)d_in[0];
  const float* Ws1 = (const float*)d_in[1];
  const float* Wn1 = (const float*)d_in[2];
  const float* b1  = (const float*)d_in[3];
  const float* Ws2 = (const float*)d_in[4];
  const float* Wn2 = (const float*)d_in[5];
  const float* b2  = (const float*)d_in[6];
  const int* src1  = (const int*)d_in[7];
  const int* dst1  = (const int*)d_in[8];
  const int* src2  = (const int*)d_in[9];
  const int* dst2  = (const int*)d_in[10];

  int*   wsI  = (int*)d_ws;
  int*   cnt1  = wsI + OFF_CNT1;
  int*   cnt2  = wsI + OFF_CNT2;
  int*   rp1   = wsI + OFF_RP1;
  int*   rp2   = wsI + OFF_RP2;
  int*   fill1 = wsI + OFF_FILL1;
  int*   fill2 = wsI + OFF_FILL2;
  int*   part  = wsI + OFF_PART;
  unsigned short* Wt    = (unsigned short*)(wsI + OFF_WT1);
  unsigned short* Wt2   = (unsigned short*)(wsI + OFF_WT2);
  int*   csr1  = wsI + OFF_CSR1;
  int*   csr2  = wsI + OFF_CSR2;
  unsigned short* aggb  = (unsigned short*)(wsI + OFF_AGG1);
  unsigned short* agg2b = (unsigned short*)(wsI + OFF_AGG1);  // aliases (agg1 dead)
  unsigned short* h = (unsigned short*)(wsI + OFF_H);
  float* out   = (float*)d_out;

  hipMemsetAsync(wsI, 0, (size_t)ZERO_INTS * sizeof(int), stream);

  init_kernel<<<HIST_B + 128 + 48, 512, 0, stream>>>(
      dst1, dst2, cnt1, cnt2, Ws1, Wn1, Wt, Ws2, Wn2, Wt2);
  scanA_kernel<<<NB_SCAN, 1024, 0, stream>>>(cnt1, part);
  scanB_kernel<<<1, 64, 0, stream>>>(part);
  scanC_kernel<<<NB_SCAN, 1024, 0, stream>>>(cnt1, part, rp1, rp2, fill1, fill2);
  {
    int blocks = (E1 + 255) / 256;
    scatter_kernel<<<blocks, 256, 0, stream>>>(src1, dst1, src2, dst2,
                                               fill1, fill2, csr1, csr2);
  }
  {
    int blocks = (N_DST1 * 64 + 255) / 256;
    reduce1_kernel<<<blocks, 256, 0, stream>>>(x, csr1, rp1, cnt1, aggb);
  }
  {
    int blocks = (N_DST1 + 63) / 64;   // 1563
    layer1_mfma_kernel<<<blocks, 256, 0, stream>>>(x, aggb, Wt, b1, h);
  }
  {
    int blocks = (N_DST2 * 64 + 255) / 256;
    reduce2_kernel<<<blocks, 256, 0, stream>>>(h, csr2, rp2, cnt2, agg2b);
  }
  {
    int blocks = (N_DST2 + 63) / 64;   // 313
    layer2_mfma_kernel<<<blocks, 256, 0, stream>>>(h, agg2b, Wt2, b2, out);
  }
}